// Round 5
// baseline (902.368 us; speedup 1.0000x reference)
//
#include <hip/hip_runtime.h>

#define HH 352
#define WW 1216
#define NB 4
#define HWSZ (HH * WW)      // 428032 pixels per plane
#define WQ 304              // quads per row
#define BHQ (HH * WQ)
#define NQ (NB * BHQ)

#define TW 64
#define TH 4
#define LW (TW + 2)
#define LROWS (TH + 4)
#define TILES_W 5           // ceil(304/64); last tile ragged (48/64 active)
#define TILES_H (HH / TH)   // 88
#define NTILES (NB * TILES_H * TILES_W)  // 1760 tiles
#define GBLK 1024                        // persistent grid: 4 blocks/CU x 256 CU
#define BANDS 8
#define PER_BAND (GBLK / BANDS)          // 128 blocks per band
#define TPB (NTILES / BANDS)             // 220 tiles per band

typedef _Float16 half4 __attribute__((ext_vector_type(4)));
typedef _Float16 half8 __attribute__((ext_vector_type(8)));

// ---------------------------------------------------------------------------
// Hand-rolled hierarchical grid barrier (correctness proven on HW r1-r4).
// sy layout (unsigned idx): cnt[band] at band*64, root at 512, gen at 640.
// ---------------------------------------------------------------------------
__device__ __forceinline__ void gsync(unsigned* sy, int band, unsigned target) {
    __syncthreads();
    if (threadIdx.x == 0) {
        unsigned* cnt  = sy + band * 64;
        unsigned* root = sy + 512;
        unsigned* gen  = sy + 640;
        unsigned old = __hip_atomic_fetch_add(cnt, 1u, __ATOMIC_ACQ_REL,
                                              __HIP_MEMORY_SCOPE_AGENT);
        if (old == PER_BAND - 1u) {
            __hip_atomic_store(cnt, 0u, __ATOMIC_RELAXED, __HIP_MEMORY_SCOPE_AGENT);
            unsigned r = __hip_atomic_fetch_add(root, 1u, __ATOMIC_ACQ_REL,
                                                __HIP_MEMORY_SCOPE_AGENT);
            if (r == BANDS - 1u) {
                __hip_atomic_store(root, 0u, __ATOMIC_RELAXED, __HIP_MEMORY_SCOPE_AGENT);
                __hip_atomic_store(gen, target, __ATOMIC_RELEASE, __HIP_MEMORY_SCOPE_AGENT);
            } else {
                while (__hip_atomic_load(gen, __ATOMIC_ACQUIRE,
                                         __HIP_MEMORY_SCOPE_AGENT) < target)
                    __builtin_amdgcn_s_sleep(4);
            }
        } else {
            while (__hip_atomic_load(gen, __ATOMIC_ACQUIRE,
                                     __HIP_MEMORY_SCOPE_AGENT) < target)
                __builtin_amdgcn_s_sleep(4);
        }
    }
    __syncthreads();
}

// ---- softmax helpers: NAMED half8 destinations, no arrays ----------------
#define SMK(W, K) do {                                                         \
    float4 _a = *(const float4*)(g1 + _gb + (long)(K) * HWSZ);                 \
    float4 _c = *(const float4*)(g2 + _gb + (long)(K) * HWSZ);                 \
    _a.x = __expf(_a.x); _a.y = __expf(_a.y);                                  \
    _a.z = __expf(_a.z); _a.w = __expf(_a.w);                                  \
    _c.x = __expf(_c.x); _c.y = __expf(_c.y);                                  \
    _c.z = __expf(_c.z); _c.w = __expf(_c.w);                                  \
    _s1.x += _a.x; _s1.y += _a.y; _s1.z += _a.z; _s1.w += _a.w;                \
    _s2.x += _c.x; _s2.y += _c.y; _s2.z += _c.z; _s2.w += _c.w;                \
    half8 _o;                                                                  \
    _o[0] = (_Float16)_a.x; _o[1] = (_Float16)_c.x;                            \
    _o[2] = (_Float16)_a.y; _o[3] = (_Float16)_c.y;                            \
    _o[4] = (_Float16)_a.z; _o[5] = (_Float16)_c.z;                            \
    _o[6] = (_Float16)_a.w; _o[7] = (_Float16)_c.w;                            \
    W = _o;                                                                    \
} while (0)

#define PMW(W) do {                                                            \
    half8 _o = W;                                                              \
    _o[0] = (_Float16)((float)_o[0] * _r1.x);                                  \
    _o[1] = (_Float16)((float)_o[1] * _r2.x);                                  \
    _o[2] = (_Float16)((float)_o[2] * _r1.y);                                  \
    _o[3] = (_Float16)((float)_o[3] * _r2.y);                                  \
    _o[4] = (_Float16)((float)_o[4] * _r1.z);                                  \
    _o[5] = (_Float16)((float)_o[5] * _r2.z);                                  \
    _o[6] = (_Float16)((float)_o[6] * _r1.w);                                  \
    _o[7] = (_Float16)((float)_o[7] * _r2.w);                                  \
    W = _o;                                                                    \
} while (0)

#define SOFTMAX9(w0,w1,w2,w3,w4,w5,w6,w7,w8, actT, bT, p0T) do {               \
    if (actT) {                                                                \
        const long _gb = (long)(bT) * 9 * HWSZ + (p0T);                        \
        float4 _s1 = make_float4(0.f, 0.f, 0.f, 0.f);                          \
        float4 _s2 = make_float4(0.f, 0.f, 0.f, 0.f);                          \
        SMK(w0, 0); SMK(w1, 1); SMK(w2, 2); SMK(w3, 3); SMK(w4, 4);            \
        SMK(w5, 5); SMK(w6, 6); SMK(w7, 7); SMK(w8, 8);                        \
        const long _fb = (long)(bT) * 2 * HWSZ + (p0T);                        \
        float4 _f1 = *(const float4*)(fuse + _fb);                             \
        float4 _f2 = *(const float4*)(fuse + _fb + HWSZ);                      \
        float4 _r1, _r2;                                                       \
        _r1.x = _f1.x / _s1.x; _r1.y = _f1.y / _s1.y;                          \
        _r1.z = _f1.z / _s1.z; _r1.w = _f1.w / _s1.w;                          \
        _r2.x = _f2.x / _s2.x; _r2.y = _f2.y / _s2.y;                          \
        _r2.z = _f2.z / _s2.z; _r2.w = _f2.w / _s2.w;                          \
        PMW(w0); PMW(w1); PMW(w2); PMW(w3); PMW(w4);                           \
        PMW(w5); PMW(w6); PMW(w7); PMW(w8);                                    \
    }                                                                          \
} while (0)

// stage one x tile + halo into LDS (f32 source at s==1, fp16 ping-pong after)
#define STAGE_TILE(xs, bT, h0T, q0T) do {                                      \
    const float*    _xb32 = x0  + (long)(bT) * HWSZ;                           \
    const _Float16* _xb16 = cur + (long)(bT) * HWSZ;                           \
    for (int _i = tid; _i < LROWS * LW; _i += 256) {                           \
        int _row = _i / LW;                                                    \
        int _qc  = _i - _row * LW;                                             \
        int _hh  = (h0T) - 2 + _row;                                           \
        int _qg  = (q0T) - 1 + _qc;                                            \
        float4 _v = make_float4(0.f, 0.f, 0.f, 0.f);                           \
        if (_hh >= 0 && _hh < HH && _qg >= 0 && _qg < WQ) {                    \
            if (s == 1) {                                                      \
                _v = *(const float4*)(_xb32 + (long)_hh * WW + _qg * 4);       \
            } else {                                                           \
                half4 _hv = *(const half4*)(_xb16 + (long)_hh * WW + _qg * 4); \
                _v = make_float4((float)_hv[0], (float)_hv[1],                 \
                                 (float)_hv[2], (float)_hv[3]);                \
            }                                                                  \
        }                                                                      \
        *(float4*)&xs[_row][_qc * 4] = _v;                                     \
    }                                                                          \
} while (0)

// ---- compute helpers: named weight vars, transient row window -------------
#define ROWW(xs, R)                                                            \
    const float* _p = &xs[ty + (R)][4 * tx + 2];                               \
    float2 _aa = *(const float2*)(_p);                                         \
    float4 _mm = *(const float4*)(_p + 2);                                     \
    float2 _zz = *(const float2*)(_p + 6);                                     \
    float _rw[8] = {_aa.x, _aa.y, _mm.x, _mm.y, _mm.z, _mm.w, _zz.x, _zz.y};

#define D1TAP(W, KX) do {                                                      \
    _oo.x = fmaf((float)W[0], _rw[0 + 1 + (KX)], _oo.x);                       \
    _oo.y = fmaf((float)W[2], _rw[1 + 1 + (KX)], _oo.y);                       \
    _oo.z = fmaf((float)W[4], _rw[2 + 1 + (KX)], _oo.z);                       \
    _oo.w = fmaf((float)W[6], _rw[3 + 1 + (KX)], _oo.w);                       \
} while (0)

#define D2TAP(W, KX) do {                                                      \
    _oo.x = fmaf((float)W[1], _rw[0 + 2 * (KX)], _oo.x);                       \
    _oo.y = fmaf((float)W[3], _rw[1 + 2 * (KX)], _oo.y);                       \
    _oo.z = fmaf((float)W[5], _rw[2 + 2 * (KX)], _oo.z);                       \
    _oo.w = fmaf((float)W[7], _rw[3 + 2 * (KX)], _oo.w);                       \
} while (0)

#define COMPUTE9(xs, w0,w1,w2,w3,w4,w5,w6,w7,w8, actT, obaseT) do {            \
    if (actT) {                                                                \
        float4 _oo = make_float4(0.f, 0.f, 0.f, 0.f);                          \
        { ROWW(xs, 0); D2TAP(w0, 0); D2TAP(w1, 1); D2TAP(w2, 2); }             \
        { ROWW(xs, 1); D1TAP(w0, 0); D1TAP(w1, 1); D1TAP(w2, 2); }             \
        { ROWW(xs, 2); D1TAP(w3, 0); D1TAP(w4, 1); D1TAP(w5, 2);               \
                       D2TAP(w3, 0); D2TAP(w4, 1); D2TAP(w5, 2); }             \
        { ROWW(xs, 3); D1TAP(w6, 0); D1TAP(w7, 1); D1TAP(w8, 2); }             \
        { ROWW(xs, 4); D2TAP(w6, 0); D2TAP(w7, 1); D2TAP(w8, 2); }             \
        if (s < 8) {                                                           \
            half4 _xo;                                                         \
            _xo[0] = (_Float16)_oo.x; _xo[1] = (_Float16)_oo.y;                \
            _xo[2] = (_Float16)_oo.z; _xo[3] = (_Float16)_oo.w;                \
            *(half4*)(nxt + (obaseT)) = _xo;                                   \
        } else {                                                               \
            *(float4*)(out + (obaseT)) = _oo;                                  \
        }                                                                      \
    }                                                                          \
} while (0)

// ---------------------------------------------------------------------------
// Persistent 2-tile fused kernel. KEY CHANGE vs r4: the 18 persistent weight
// fragments are NAMED half8 variables, not arrays. r2/r3/r4 signature
// (VGPR_Count pinned at 64, ~96MB scratch writes regardless of launch-bounds)
// indicates the tv[] allocas were demoted to scratch in the middle-end
// (SROA failure across the barrier loop), so no RA budget could help.
// Named scalars cannot be demoted. waves_per_eu(4,4) keeps the 128-VGPR
// budget for the ~100-reg peak.
// ---------------------------------------------------------------------------
__global__ __launch_bounds__(256)
__attribute__((amdgpu_waves_per_eu(4, 4)))
void fused_all(
    const float* __restrict__ g1, const float* __restrict__ g2,
    const float* __restrict__ fuse, const float* __restrict__ x0,
    float* __restrict__ out, _Float16* __restrict__ bufA,
    _Float16* __restrict__ bufB, unsigned* __restrict__ sy)
{
    __shared__ float xsA[LROWS][LW * 4];
    __shared__ float xsB[LROWS][LW * 4];

    const int tid  = threadIdx.x;
    const int bid  = blockIdx.x;
    const int band = bid & 7;
    const int idx  = bid >> 3;          // 0..127 within band

    const int tx = tid & (TW - 1);
    const int ty = tid >> 6;

    // ---- tile A ----
    const int tileA = band * TPB + idx;
    int tXA = tileA % TILES_W; int rrA = tileA / TILES_W;
    int tYA = rrA % TILES_H;   int bA  = rrA / TILES_H;
    int q0A = tXA * TW, h0A = tYA * TH;
    int qaA = q0A + tx; const bool actA = (qaA < WQ);
    int p0A = (h0A + ty) * WW + qaA * 4;
    int obaseA = bA * HWSZ + p0A;

    // ---- tile B (92 of 128 blocks per band) ----
    const bool hasB = (PER_BAND + idx) < TPB;
    const int tileB = band * TPB + (hasB ? (PER_BAND + idx) : idx);
    int tXB = tileB % TILES_W; int rrB = tileB / TILES_W;
    int tYB = rrB % TILES_H;   int bB  = rrB / TILES_H;
    int q0B = tXB * TW, h0B = tYB * TH;
    int qaB = q0B + tx; const bool actB = hasB && (qaB < WQ);
    int p0B = (h0B + ty) * WW + qaB * 4;
    int obaseB = bB * HWSZ + p0B;

    // ---- persistent premultiplied fp16 weights: 18 NAMED half8 (72 VGPR) ---
    half8 wA0, wA1, wA2, wA3, wA4, wA5, wA6, wA7, wA8;
    half8 wB0, wB1, wB2, wB3, wB4, wB5, wB6, wB7, wB8;
    SOFTMAX9(wA0, wA1, wA2, wA3, wA4, wA5, wA6, wA7, wA8, actA, bA, p0A);
    if (hasB)
        SOFTMAX9(wB0, wB1, wB2, wB3, wB4, wB5, wB6, wB7, wB8, actB, bB, p0B);

    // ---- 8 propagation steps, grid-synced, x ping-ponged fp16 ----
    const _Float16* cur = bufA;   // not dereferenced at s==1
    _Float16* nxt = bufA;

#pragma unroll 1
    for (int s = 1; s <= 8; ++s) {
        STAGE_TILE(xsA, bA, h0A, q0A);
        if (hasB) STAGE_TILE(xsB, bB, h0B, q0B);
        __syncthreads();

        COMPUTE9(xsA, wA0, wA1, wA2, wA3, wA4, wA5, wA6, wA7, wA8,
                 actA, obaseA);
        if (hasB)
            COMPUTE9(xsB, wB0, wB1, wB2, wB3, wB4, wB5, wB6, wB7, wB8,
                     actB, obaseB);

        if (s < 8) gsync(sy, band, (unsigned)s);   // also guards xs reuse
        else break;

        cur = nxt;
        nxt = (cur == bufA) ? bufB : bufA;
    }
}

// ===========================================================================
// Fallback: verified 8-dispatch pipeline (246 µs), used only if memset or
// cooperative launch is rejected.
// ===========================================================================
__global__ __launch_bounds__(256, 4) void softmax_prop1_kernel(
    const float* __restrict__ g1, const float* __restrict__ g2,
    const float* __restrict__ fuse, const float* __restrict__ x0,
    _Float16* __restrict__ kk, _Float16* __restrict__ x1) {
    int q = blockIdx.x * 256 + threadIdx.x;
    if (q >= NQ) return;
    int b   = q / BHQ;
    int rem = q - b * BHQ;
    int h   = rem / WQ;
    int wq  = rem - h * WQ;
    int w0  = wq * 4;
    long gbase = (long)b * 9 * HWSZ + (long)rem * 4;
    long fbase = (long)b * 2 * HWSZ + (long)rem * 4;

    float4 t[18];
#pragma unroll
    for (int k = 0; k < 9; k++) t[k]     = *(const float4*)(g1 + gbase + (long)k * HWSZ);
#pragma unroll
    for (int k = 0; k < 9; k++) t[9 + k] = *(const float4*)(g2 + gbase + (long)k * HWSZ);
    float4 f1 = *(const float4*)(fuse + fbase);
    float4 f2 = *(const float4*)(fuse + fbase + HWSZ);

    float s1[4] = {0.f, 0.f, 0.f, 0.f}, s2[4] = {0.f, 0.f, 0.f, 0.f};
#pragma unroll
    for (int k = 0; k < 9; k++) {
        t[k].x = __expf(t[k].x); s1[0] += t[k].x;
        t[k].y = __expf(t[k].y); s1[1] += t[k].y;
        t[k].z = __expf(t[k].z); s1[2] += t[k].z;
        t[k].w = __expf(t[k].w); s1[3] += t[k].w;
    }
#pragma unroll
    for (int k = 9; k < 18; k++) {
        t[k].x = __expf(t[k].x); s2[0] += t[k].x;
        t[k].y = __expf(t[k].y); s2[1] += t[k].y;
        t[k].z = __expf(t[k].z); s2[2] += t[k].z;
        t[k].w = __expf(t[k].w); s2[3] += t[k].w;
    }
    float r1[4], r2[4];
    r1[0] = f1.x / s1[0]; r1[1] = f1.y / s1[1]; r1[2] = f1.z / s1[2]; r1[3] = f1.w / s1[3];
    r2[0] = f2.x / s2[0]; r2[1] = f2.y / s2[1]; r2[2] = f2.z / s2[2]; r2[3] = f2.w / s2[3];

    long obase = gbase * 2;
    half8 kv[9];
#pragma unroll
    for (int k = 0; k < 9; k++) {
        half8 o;
        o[0] = (_Float16)(t[k].x * r1[0]); o[1] = (_Float16)(t[9 + k].x * r2[0]);
        o[2] = (_Float16)(t[k].y * r1[1]); o[3] = (_Float16)(t[9 + k].y * r2[1]);
        o[4] = (_Float16)(t[k].z * r1[2]); o[5] = (_Float16)(t[9 + k].z * r2[2]);
        o[6] = (_Float16)(t[k].w * r1[3]); o[7] = (_Float16)(t[9 + k].w * r2[3]);
        kv[k] = o;
        *(half8*)(kk + obase + (long)k * HWSZ * 2) = o;
    }

    const float* xb = x0 + (long)b * HWSZ;
    float rb[5][8];
#pragma unroll
    for (int r = 0; r < 5; r++) {
        int hh = h - 2 + r;
        bool rv = (hh >= 0) && (hh < HH);
        const float* rp = xb + (long)hh * WW;
        float4 mid = rv ? *(const float4*)(rp + w0) : make_float4(0.f, 0.f, 0.f, 0.f);
        float2 lft = (rv && w0 > 0) ? *(const float2*)(rp + w0 - 2) : make_float2(0.f, 0.f);
        float2 rgt = (rv && (w0 + 5) < WW) ? *(const float2*)(rp + w0 + 4) : make_float2(0.f, 0.f);
        rb[r][0] = lft.x; rb[r][1] = lft.y;
        rb[r][2] = mid.x; rb[r][3] = mid.y; rb[r][4] = mid.z; rb[r][5] = mid.w;
        rb[r][6] = rgt.x; rb[r][7] = rgt.y;
    }
    float o[4] = {0.f, 0.f, 0.f, 0.f};
#pragma unroll
    for (int ky = 0; ky < 3; ky++)
#pragma unroll
        for (int kx = 0; kx < 3; kx++) {
            int k = ky * 3 + kx;
#pragma unroll
            for (int j = 0; j < 4; j++) {
                o[j] = fmaf((float)kv[k][2 * j],     rb[ky + 1][j + 1 + kx], o[j]);
                o[j] = fmaf((float)kv[k][2 * j + 1], rb[2 * ky][j + 2 * kx], o[j]);
            }
        }
    half4 xo;
    xo[0] = (_Float16)o[0]; xo[1] = (_Float16)o[1];
    xo[2] = (_Float16)o[2]; xo[3] = (_Float16)o[3];
    *(half4*)(x1 + (long)b * HWSZ + (long)rem * 4) = xo;
}

template <int OUT16>
__global__ __launch_bounds__(256, 4) void prop_kernel(
    const _Float16* __restrict__ kk,
    const _Float16* __restrict__ xin, void* __restrict__ xout_) {
    __shared__ float xs[LROWS][LW * 4];

    int tid = threadIdx.x;
    int bidx = blockIdx.x;
    int tX = bidx % TILES_W;
    int r1 = bidx / TILES_W;
    int tY = r1 % TILES_H;
    int b  = r1 / TILES_H;
    int q0 = tX * TW;
    int h0 = tY * TH;

    const _Float16* xb = xin + (long)b * HWSZ;

#pragma unroll
    for (int i = tid; i < LROWS * LW; i += 256) {
        int row = i / LW;
        int qc  = i - row * LW;
        int h   = h0 - 2 + row;
        int qg  = q0 - 1 + qc;
        float4 v = make_float4(0.f, 0.f, 0.f, 0.f);
        if (h >= 0 && h < HH && qg >= 0 && qg < WQ) {
            half4 hv = *(const half4*)(xb + (long)h * WW + qg * 4);
            v = make_float4((float)hv[0], (float)hv[1], (float)hv[2], (float)hv[3]);
        }
        *(float4*)&xs[row][qc * 4] = v;
    }
    __syncthreads();

    int tx = tid & (TW - 1);
    int ty = tid >> 6;
    int qa = q0 + tx;
    if (qa >= WQ) return;

    int h = h0 + ty;
    long p0 = (long)h * WW + qa * 4;
    long kbase = ((long)b * 9 * HWSZ + p0) * 2;

    half8 kv[9];
#pragma unroll
    for (int k = 0; k < 9; k++)
        kv[k] = *(const half8*)(kk + kbase + (long)k * HWSZ * 2);

    float rb[5][8];
#pragma unroll
    for (int r = 0; r < 5; r++) {
        const float* p = &xs[ty + r][4 * tx + 2];
        float2 a = *(const float2*)(p);
        float4 m = *(const float4*)(p + 2);
        float2 z = *(const float2*)(p + 6);
        rb[r][0] = a.x; rb[r][1] = a.y;
        rb[r][2] = m.x; rb[r][3] = m.y; rb[r][4] = m.z; rb[r][5] = m.w;
        rb[r][6] = z.x; rb[r][7] = z.y;
    }

    float o[4] = {0.f, 0.f, 0.f, 0.f};
#pragma unroll
    for (int ky = 0; ky < 3; ky++)
#pragma unroll
        for (int kx = 0; kx < 3; kx++) {
            int k = ky * 3 + kx;
#pragma unroll
            for (int j = 0; j < 4; j++) {
                o[j] = fmaf((float)kv[k][2 * j],     rb[ky + 1][j + 1 + kx], o[j]);
                o[j] = fmaf((float)kv[k][2 * j + 1], rb[2 * ky][j + 2 * kx], o[j]);
            }
        }

    if (OUT16) {
        half4 xo;
        xo[0] = (_Float16)o[0]; xo[1] = (_Float16)o[1];
        xo[2] = (_Float16)o[2]; xo[3] = (_Float16)o[3];
        *(half4*)((_Float16*)xout_ + (long)b * HWSZ + p0) = xo;
    } else {
        *(float4*)((float*)xout_ + (long)b * HWSZ + p0) =
            make_float4(o[0], o[1], o[2], o[3]);
    }
}

extern "C" void kernel_launch(void* const* d_in, const int* in_sizes, int n_in,
                              void* d_out, int out_size, void* d_ws, size_t ws_size,
                              hipStream_t stream) {
    const float* g1   = (const float*)d_in[0];
    const float* g2   = (const float*)d_in[1];
    const float* fuse = (const float*)d_in[2];
    const float* x    = (const float*)d_in[3];
    float* out = (float*)d_out;

    // ws layout: [sync 4KB | rest of kk region] kk (61.6 MB) | bufA | bufB.
    // Persistent path uses sync+bufA/bufB; fallback uses kk+bufA/bufB.
    _Float16* kk   = (_Float16*)d_ws;
    _Float16* bufA = kk + (size_t)NB * 9 * HWSZ * 2;
    _Float16* bufB = bufA + (size_t)NB * HWSZ;
    unsigned* sy   = (unsigned*)d_ws;

    hipError_t err = hipMemsetAsync(sy, 0, 4096, stream);
    if (err == hipSuccess) {
        void* args[] = {(void*)&g1, (void*)&g2, (void*)&fuse, (void*)&x,
                        (void*)&out, (void*)&bufA, (void*)&bufB, (void*)&sy};
        err = hipLaunchCooperativeKernel(
            reinterpret_cast<void*>(fused_all), dim3(GBLK), dim3(256), args, 0, stream);
        if (err == hipSuccess) return;
    }
    (void)hipGetLastError();  // clear sticky error; take the fallback path

    int sm_blocks = (NQ + 255) / 256;   // 1672
    softmax_prop1_kernel<<<sm_blocks, 256, 0, stream>>>(g1, g2, fuse, x, kk, bufA);

    int pr_blocks = NB * TILES_H * TILES_W;   // 1760
    prop_kernel<1><<<pr_blocks, 256, 0, stream>>>(kk, bufA, bufB);
    prop_kernel<1><<<pr_blocks, 256, 0, stream>>>(kk, bufB, bufA);
    prop_kernel<1><<<pr_blocks, 256, 0, stream>>>(kk, bufA, bufB);
    prop_kernel<1><<<pr_blocks, 256, 0, stream>>>(kk, bufB, bufA);
    prop_kernel<1><<<pr_blocks, 256, 0, stream>>>(kk, bufA, bufB);
    prop_kernel<1><<<pr_blocks, 256, 0, stream>>>(kk, bufB, bufA);
    prop_kernel<0><<<pr_blocks, 256, 0, stream>>>(kk, bufA, out);
}

// Round 6
// 263.020 us; speedup vs baseline: 3.4308x; 3.4308x over previous
//
#include <hip/hip_runtime.h>

#define HH 352
#define WW 1216
#define NB 4
#define HWSZ (HH * WW)      // 428032 pixels per plane
#define WQ 304              // quads per row
#define BHQ (HH * WQ)
#define NQ (NB * BHQ)

typedef _Float16 half4 __attribute__((ext_vector_type(4)));
typedef _Float16 half8 __attribute__((ext_vector_type(8)));

// ---------------------------------------------------------------------------
// Step 1 kernel (VERBATIM from the verified 246.5 us pipeline):
// softmax+premul for both guided tensors AND propagation step 1.
// ---------------------------------------------------------------------------
__global__ __launch_bounds__(256, 4) void softmax_prop1_kernel(
    const float* __restrict__ g1, const float* __restrict__ g2,
    const float* __restrict__ fuse, const float* __restrict__ x0,
    _Float16* __restrict__ kk, _Float16* __restrict__ x1) {
    int q = blockIdx.x * 256 + threadIdx.x;
    if (q >= NQ) return;
    int b   = q / BHQ;
    int rem = q - b * BHQ;
    int h   = rem / WQ;
    int wq  = rem - h * WQ;
    int w0  = wq * 4;
    long gbase = (long)b * 9 * HWSZ + (long)rem * 4;
    long fbase = (long)b * 2 * HWSZ + (long)rem * 4;

    float4 t[18];
#pragma unroll
    for (int k = 0; k < 9; k++) t[k]     = *(const float4*)(g1 + gbase + (long)k * HWSZ);
#pragma unroll
    for (int k = 0; k < 9; k++) t[9 + k] = *(const float4*)(g2 + gbase + (long)k * HWSZ);
    float4 f1 = *(const float4*)(fuse + fbase);
    float4 f2 = *(const float4*)(fuse + fbase + HWSZ);

    float s1[4] = {0.f, 0.f, 0.f, 0.f}, s2[4] = {0.f, 0.f, 0.f, 0.f};
#pragma unroll
    for (int k = 0; k < 9; k++) {
        t[k].x = __expf(t[k].x); s1[0] += t[k].x;
        t[k].y = __expf(t[k].y); s1[1] += t[k].y;
        t[k].z = __expf(t[k].z); s1[2] += t[k].z;
        t[k].w = __expf(t[k].w); s1[3] += t[k].w;
    }
#pragma unroll
    for (int k = 9; k < 18; k++) {
        t[k].x = __expf(t[k].x); s2[0] += t[k].x;
        t[k].y = __expf(t[k].y); s2[1] += t[k].y;
        t[k].z = __expf(t[k].z); s2[2] += t[k].z;
        t[k].w = __expf(t[k].w); s2[3] += t[k].w;
    }
    float r1[4], r2[4];
    r1[0] = f1.x / s1[0]; r1[1] = f1.y / s1[1]; r1[2] = f1.z / s1[2]; r1[3] = f1.w / s1[3];
    r2[0] = f2.x / s2[0]; r2[1] = f2.y / s2[1]; r2[2] = f2.z / s2[2]; r2[3] = f2.w / s2[3];

    long obase = gbase * 2;
    half8 kv[9];
#pragma unroll
    for (int k = 0; k < 9; k++) {
        half8 o;
        o[0] = (_Float16)(t[k].x * r1[0]); o[1] = (_Float16)(t[9 + k].x * r2[0]);
        o[2] = (_Float16)(t[k].y * r1[1]); o[3] = (_Float16)(t[9 + k].y * r2[1]);
        o[4] = (_Float16)(t[k].z * r1[2]); o[5] = (_Float16)(t[9 + k].z * r2[2]);
        o[6] = (_Float16)(t[k].w * r1[3]); o[7] = (_Float16)(t[9 + k].w * r2[3]);
        kv[k] = o;
        *(half8*)(kk + obase + (long)k * HWSZ * 2) = o;
    }

    const float* xb = x0 + (long)b * HWSZ;
    float rb[5][8];
#pragma unroll
    for (int r = 0; r < 5; r++) {
        int hh = h - 2 + r;
        bool rv = (hh >= 0) && (hh < HH);
        const float* rp = xb + (long)hh * WW;
        float4 mid = rv ? *(const float4*)(rp + w0) : make_float4(0.f, 0.f, 0.f, 0.f);
        float2 lft = (rv && w0 > 0) ? *(const float2*)(rp + w0 - 2) : make_float2(0.f, 0.f);
        float2 rgt = (rv && (w0 + 5) < WW) ? *(const float2*)(rp + w0 + 4) : make_float2(0.f, 0.f);
        rb[r][0] = lft.x; rb[r][1] = lft.y;
        rb[r][2] = mid.x; rb[r][3] = mid.y; rb[r][4] = mid.z; rb[r][5] = mid.w;
        rb[r][6] = rgt.x; rb[r][7] = rgt.y;
    }
    float o[4] = {0.f, 0.f, 0.f, 0.f};
#pragma unroll
    for (int ky = 0; ky < 3; ky++)
#pragma unroll
        for (int kx = 0; kx < 3; kx++) {
            int k = ky * 3 + kx;
#pragma unroll
            for (int j = 0; j < 4; j++) {
                o[j] = fmaf((float)kv[k][2 * j],     rb[ky + 1][j + 1 + kx], o[j]);
                o[j] = fmaf((float)kv[k][2 * j + 1], rb[2 * ky][j + 2 * kx], o[j]);
            }
        }
    half4 xo;
    xo[0] = (_Float16)o[0]; xo[1] = (_Float16)o[1];
    xo[2] = (_Float16)o[2]; xo[3] = (_Float16)o[3];
    *(half4*)(x1 + (long)b * HWSZ + (long)rem * 4) = xo;
}

// ---------------------------------------------------------------------------
// Single-step prop kernel (VERBATIM from verified pipeline) — used for the
// final step with f32 output.
// ---------------------------------------------------------------------------
#define TW 64
#define TH 4
#define LW (TW + 2)
#define LROWS (TH + 4)
#define TILES_W 5
#define TILES_H (HH / TH)   // 88

template <int OUT16>
__global__ __launch_bounds__(256, 4) void prop_kernel(
    const _Float16* __restrict__ kk,
    const _Float16* __restrict__ xin, void* __restrict__ xout_) {
    __shared__ float xs[LROWS][LW * 4];

    int tid = threadIdx.x;
    int bidx = blockIdx.x;
    int tX = bidx % TILES_W;
    int r1 = bidx / TILES_W;
    int tY = r1 % TILES_H;
    int b  = r1 / TILES_H;
    int q0 = tX * TW;
    int h0 = tY * TH;

    const _Float16* xb = xin + (long)b * HWSZ;

#pragma unroll
    for (int i = tid; i < LROWS * LW; i += 256) {
        int row = i / LW;
        int qc  = i - row * LW;
        int h   = h0 - 2 + row;
        int qg  = q0 - 1 + qc;
        float4 v = make_float4(0.f, 0.f, 0.f, 0.f);
        if (h >= 0 && h < HH && qg >= 0 && qg < WQ) {
            half4 hv = *(const half4*)(xb + (long)h * WW + qg * 4);
            v = make_float4((float)hv[0], (float)hv[1], (float)hv[2], (float)hv[3]);
        }
        *(float4*)&xs[row][qc * 4] = v;
    }
    __syncthreads();

    int tx = tid & (TW - 1);
    int ty = tid >> 6;
    int qa = q0 + tx;
    if (qa >= WQ) return;

    int h = h0 + ty;
    long p0 = (long)h * WW + qa * 4;
    long kbase = ((long)b * 9 * HWSZ + p0) * 2;

    half8 kv[9];
#pragma unroll
    for (int k = 0; k < 9; k++)
        kv[k] = *(const half8*)(kk + kbase + (long)k * HWSZ * 2);

    float rb[5][8];
#pragma unroll
    for (int r = 0; r < 5; r++) {
        const float* p = &xs[ty + r][4 * tx + 2];
        float2 a = *(const float2*)(p);
        float4 m = *(const float4*)(p + 2);
        float2 z = *(const float2*)(p + 6);
        rb[r][0] = a.x; rb[r][1] = a.y;
        rb[r][2] = m.x; rb[r][3] = m.y; rb[r][4] = m.z; rb[r][5] = m.w;
        rb[r][6] = z.x; rb[r][7] = z.y;
    }

    float o[4] = {0.f, 0.f, 0.f, 0.f};
#pragma unroll
    for (int ky = 0; ky < 3; ky++)
#pragma unroll
        for (int kx = 0; kx < 3; kx++) {
            int k = ky * 3 + kx;
#pragma unroll
            for (int j = 0; j < 4; j++) {
                o[j] = fmaf((float)kv[k][2 * j],     rb[ky + 1][j + 1 + kx], o[j]);
                o[j] = fmaf((float)kv[k][2 * j + 1], rb[2 * ky][j + 2 * kx], o[j]);
            }
        }

    if (OUT16) {
        half4 xo;
        xo[0] = (_Float16)o[0]; xo[1] = (_Float16)o[1];
        xo[2] = (_Float16)o[2]; xo[3] = (_Float16)o[3];
        *(half4*)((_Float16*)xout_ + (long)b * HWSZ + p0) = xo;
    } else {
        *(float4*)((float*)xout_ + (long)b * HWSZ + p0) =
            make_float4(o[0], o[1], o[2], o[3]);
    }
}

// ---------------------------------------------------------------------------
// NEW: 2-step fused prop kernel (temporal blocking). Per block:
//   stage  (DTH+8) x (DTW+4 quads) of x_s          -> xs0 (f32 LDS)
//   phase1 (DTH+4) x (DTW+2 quads) step s+1 halo'd -> xs1 (f32 LDS, no fp16
//          rounding of the intra-pair intermediate; OOB rows/cols forced 0)
//   phase2  DTH    x  DTW core, step s+2           -> global fp16
// kk read once per pair (halo dup 1.55x, phase-2 re-reads hit L1/L2).
// ---------------------------------------------------------------------------
#define DTW 64              // core quads per tile
#define DTH 8               // core rows per tile
#define DXW (DTW + 4)       // staged quads (halo +-2 quads = +-8 px)
#define DSR (DTH + 8)       // staged rows  (halo +-4)
#define DIW (DTW + 2)       // intermediate quads (halo +-1 quad)
#define DIR (DTH + 4)       // intermediate rows  (halo +-2)
#define DTILES_W 5          // ceil(304/64); last tile ragged
#define DTILES_H (HH / DTH) // 44

// 9-tap dual-dilation conv at one quad; window cols CB..CB+7 = px -2..+5
// relative to the quad, rows RB..RB+4 = h-2..h+2. KV preloaded (9x half8).
#define CONV9(XS, RB, CB, KV, OO) do {                                         \
    _Pragma("unroll")                                                          \
    for (int _r = 0; _r < 5; _r++) {                                           \
        const float* _p = &XS[(RB) + _r][(CB)];                                \
        float2 _aa = *(const float2*)(_p);                                     \
        float4 _mm = *(const float4*)(_p + 2);                                 \
        float2 _zz = *(const float2*)(_p + 6);                                 \
        float _rw[8] = {_aa.x, _aa.y, _mm.x, _mm.y,                            \
                        _mm.z, _mm.w, _zz.x, _zz.y};                           \
        if (_r >= 1 && _r <= 3) {                                              \
            const int _ky = _r - 1;                                            \
            _Pragma("unroll")                                                  \
            for (int _kx = 0; _kx < 3; _kx++) {                                \
                const int _k = _ky * 3 + _kx;                                  \
                _Pragma("unroll")                                              \
                for (int _j = 0; _j < 4; _j++)                                 \
                    OO[_j] = fmaf((float)KV[_k][2 * _j],                       \
                                  _rw[_j + 1 + _kx], OO[_j]);                  \
            }                                                                  \
        }                                                                      \
        if ((_r & 1) == 0) {                                                   \
            const int _ky = _r >> 1;                                           \
            _Pragma("unroll")                                                  \
            for (int _kx = 0; _kx < 3; _kx++) {                                \
                const int _k = _ky * 3 + _kx;                                  \
                _Pragma("unroll")                                              \
                for (int _j = 0; _j < 4; _j++)                                 \
                    OO[_j] = fmaf((float)KV[_k][2 * _j + 1],                   \
                                  _rw[_j + 2 * _kx], OO[_j]);                  \
            }                                                                  \
        }                                                                      \
    }                                                                          \
} while (0)

template <int OUT16>
__global__ __launch_bounds__(256, 4) void prop2_kernel(
    const _Float16* __restrict__ kk,
    const _Float16* __restrict__ xin, void* __restrict__ xout_) {
    __shared__ float xs0[DSR][DXW * 4];   // 16 x 272 f32 = 17.4 KB
    __shared__ float xs1[DIR][DIW * 4];   // 12 x 264 f32 = 12.7 KB

    const int tid  = threadIdx.x;
    const int bidx = blockIdx.x;
    const int tX = bidx % DTILES_W;
    const int r1 = bidx / DTILES_W;
    const int tY = r1 % DTILES_H;
    const int b  = r1 / DTILES_H;
    const int q0 = tX * DTW;
    const int h0 = tY * DTH;

    const _Float16* xb = xin + (long)b * HWSZ;
    const _Float16* kb = kk + (long)b * 9 * HWSZ * 2;

    // ---- stage x_s tile + halo (fp16 -> f32) ----
    for (int i = tid; i < DSR * DXW; i += 256) {
        int row = i / DXW;
        int qc  = i - row * DXW;
        int h   = h0 - 4 + row;
        int qg  = q0 - 2 + qc;
        float4 v = make_float4(0.f, 0.f, 0.f, 0.f);
        if (h >= 0 && h < HH && qg >= 0 && qg < WQ) {
            half4 hv = *(const half4*)(xb + (long)h * WW + qg * 4);
            v = make_float4((float)hv[0], (float)hv[1], (float)hv[2], (float)hv[3]);
        }
        *(float4*)&xs0[row][qc * 4] = v;
    }
    __syncthreads();

    // ---- phase 1: step s+1 on halo'd footprint, f32 in LDS ----
    // task quad (tr, qc): global row h0-2+tr, global quad q0-1+qc.
    // window in xs0: rows tr..tr+4 (= h-2..h+2), col base dword 4*qc+2
    //   (quad q0-1+qc is xs0 col qc+1; base px = quad_start - 2).
    for (int t = tid; t < DIR * DIW; t += 256) {
        int tr = t / DIW;
        int qc = t - tr * DIW;
        int h  = h0 - 2 + tr;
        int qg = q0 - 1 + qc;
        float oo[4] = {0.f, 0.f, 0.f, 0.f};
        if (h >= 0 && h < HH && qg >= 0 && qg < WQ) {
            long p = (long)h * WW + qg * 4;
            half8 kv[9];
#pragma unroll
            for (int k = 0; k < 9; k++)
                kv[k] = *(const half8*)(kb + p * 2 + (long)k * HWSZ * 2);
            CONV9(xs0, tr, 4 * qc + 2, kv, oo);
        }
        *(float4*)&xs1[tr][qc * 4] = make_float4(oo[0], oo[1], oo[2], oo[3]);
    }
    __syncthreads();

    // ---- phase 2: step s+2 on core tile -> global ----
    // task quad (tr, qc): global row h0+tr, global quad q0+qc.
    // window in xs1: rows tr..tr+4 (= h-2..h+2), col base dword 4*qc+2
    //   (quad q0+qc is xs1 col qc+1).
    for (int t = tid; t < DTH * DTW; t += 256) {
        int tr = t >> 6;        // /DTW
        int qc = t & (DTW - 1);
        int qg = q0 + qc;
        if (qg >= WQ) continue; // ragged last tile column (no barrier below)
        int h  = h0 + tr;
        long p = (long)h * WW + qg * 4;
        half8 kv[9];
#pragma unroll
        for (int k = 0; k < 9; k++)
            kv[k] = *(const half8*)(kb + p * 2 + (long)k * HWSZ * 2);
        float oo[4] = {0.f, 0.f, 0.f, 0.f};
        CONV9(xs1, tr, 4 * qc + 2, kv, oo);

        long ob = (long)b * HWSZ + p;
        if (OUT16) {
            half4 xo;
            xo[0] = (_Float16)oo[0]; xo[1] = (_Float16)oo[1];
            xo[2] = (_Float16)oo[2]; xo[3] = (_Float16)oo[3];
            *(half4*)((_Float16*)xout_ + ob) = xo;
        } else {
            *(float4*)((float*)xout_ + ob) =
                make_float4(oo[0], oo[1], oo[2], oo[3]);
        }
    }
}

extern "C" void kernel_launch(void* const* d_in, const int* in_sizes, int n_in,
                              void* d_out, int out_size, void* d_ws, size_t ws_size,
                              hipStream_t stream) {
    const float* g1   = (const float*)d_in[0];
    const float* g2   = (const float*)d_in[1];
    const float* fuse = (const float*)d_in[2];
    const float* x    = (const float*)d_in[3];
    float* out = (float*)d_out;

    // ws: kk (61.6 MB) | bufA fp16 (3.4 MB) | bufB fp16 (3.4 MB)
    _Float16* kk   = (_Float16*)d_ws;
    _Float16* bufA = kk + (size_t)NB * 9 * HWSZ * 2;
    _Float16* bufB = bufA + (size_t)NB * HWSZ;

    int sm_blocks = (NQ + 255) / 256;                 // 1672
    softmax_prop1_kernel<<<sm_blocks, 256, 0, stream>>>(g1, g2, fuse, x, kk, bufA);  // step 1

    int p2_blocks = NB * DTILES_H * DTILES_W;         // 880
    prop2_kernel<1><<<p2_blocks, 256, 0, stream>>>(kk, bufA, bufB);  // steps 2,3
    prop2_kernel<1><<<p2_blocks, 256, 0, stream>>>(kk, bufB, bufA);  // steps 4,5
    prop2_kernel<1><<<p2_blocks, 256, 0, stream>>>(kk, bufA, bufB);  // steps 6,7

    int pr_blocks = NB * TILES_H * TILES_W;           // 1760
    prop_kernel<0><<<pr_blocks, 256, 0, stream>>>(kk, bufB, out);    // step 8 (f32)
}

// Round 7
// 253.502 us; speedup vs baseline: 3.5596x; 1.0375x over previous
//
#include <hip/hip_runtime.h>

#define HH 352
#define WW 1216
#define NB 4
#define HWSZ (HH * WW)      // 428032 pixels per plane
#define WQ 304              // quads per row
#define BHQ (HH * WQ)
#define NQ (NB * BHQ)

typedef _Float16 half4 __attribute__((ext_vector_type(4)));
typedef _Float16 half8 __attribute__((ext_vector_type(8)));

// ---------------------------------------------------------------------------
// Step 1 kernel (VERBATIM from the verified 246.5 us pipeline):
// softmax+premul for both guided tensors AND propagation step 1.
// ---------------------------------------------------------------------------
__global__ __launch_bounds__(256, 4) void softmax_prop1_kernel(
    const float* __restrict__ g1, const float* __restrict__ g2,
    const float* __restrict__ fuse, const float* __restrict__ x0,
    _Float16* __restrict__ kk, _Float16* __restrict__ x1) {
    int q = blockIdx.x * 256 + threadIdx.x;
    if (q >= NQ) return;
    int b   = q / BHQ;
    int rem = q - b * BHQ;
    int h   = rem / WQ;
    int wq  = rem - h * WQ;
    int w0  = wq * 4;
    long gbase = (long)b * 9 * HWSZ + (long)rem * 4;
    long fbase = (long)b * 2 * HWSZ + (long)rem * 4;

    float4 t[18];
#pragma unroll
    for (int k = 0; k < 9; k++) t[k]     = *(const float4*)(g1 + gbase + (long)k * HWSZ);
#pragma unroll
    for (int k = 0; k < 9; k++) t[9 + k] = *(const float4*)(g2 + gbase + (long)k * HWSZ);
    float4 f1 = *(const float4*)(fuse + fbase);
    float4 f2 = *(const float4*)(fuse + fbase + HWSZ);

    float s1[4] = {0.f, 0.f, 0.f, 0.f}, s2[4] = {0.f, 0.f, 0.f, 0.f};
#pragma unroll
    for (int k = 0; k < 9; k++) {
        t[k].x = __expf(t[k].x); s1[0] += t[k].x;
        t[k].y = __expf(t[k].y); s1[1] += t[k].y;
        t[k].z = __expf(t[k].z); s1[2] += t[k].z;
        t[k].w = __expf(t[k].w); s1[3] += t[k].w;
    }
#pragma unroll
    for (int k = 9; k < 18; k++) {
        t[k].x = __expf(t[k].x); s2[0] += t[k].x;
        t[k].y = __expf(t[k].y); s2[1] += t[k].y;
        t[k].z = __expf(t[k].z); s2[2] += t[k].z;
        t[k].w = __expf(t[k].w); s2[3] += t[k].w;
    }
    float r1[4], r2[4];
    r1[0] = f1.x / s1[0]; r1[1] = f1.y / s1[1]; r1[2] = f1.z / s1[2]; r1[3] = f1.w / s1[3];
    r2[0] = f2.x / s2[0]; r2[1] = f2.y / s2[1]; r2[2] = f2.z / s2[2]; r2[3] = f2.w / s2[3];

    long obase = gbase * 2;
    half8 kv[9];
#pragma unroll
    for (int k = 0; k < 9; k++) {
        half8 o;
        o[0] = (_Float16)(t[k].x * r1[0]); o[1] = (_Float16)(t[9 + k].x * r2[0]);
        o[2] = (_Float16)(t[k].y * r1[1]); o[3] = (_Float16)(t[9 + k].y * r2[1]);
        o[4] = (_Float16)(t[k].z * r1[2]); o[5] = (_Float16)(t[9 + k].z * r2[2]);
        o[6] = (_Float16)(t[k].w * r1[3]); o[7] = (_Float16)(t[9 + k].w * r2[3]);
        kv[k] = o;
        *(half8*)(kk + obase + (long)k * HWSZ * 2) = o;
    }

    const float* xb = x0 + (long)b * HWSZ;
    float rb[5][8];
#pragma unroll
    for (int r = 0; r < 5; r++) {
        int hh = h - 2 + r;
        bool rv = (hh >= 0) && (hh < HH);
        const float* rp = xb + (long)hh * WW;
        float4 mid = rv ? *(const float4*)(rp + w0) : make_float4(0.f, 0.f, 0.f, 0.f);
        float2 lft = (rv && w0 > 0) ? *(const float2*)(rp + w0 - 2) : make_float2(0.f, 0.f);
        float2 rgt = (rv && (w0 + 5) < WW) ? *(const float2*)(rp + w0 + 4) : make_float2(0.f, 0.f);
        rb[r][0] = lft.x; rb[r][1] = lft.y;
        rb[r][2] = mid.x; rb[r][3] = mid.y; rb[r][4] = mid.z; rb[r][5] = mid.w;
        rb[r][6] = rgt.x; rb[r][7] = rgt.y;
    }
    float o[4] = {0.f, 0.f, 0.f, 0.f};
#pragma unroll
    for (int ky = 0; ky < 3; ky++)
#pragma unroll
        for (int kx = 0; kx < 3; kx++) {
            int k = ky * 3 + kx;
#pragma unroll
            for (int j = 0; j < 4; j++) {
                o[j] = fmaf((float)kv[k][2 * j],     rb[ky + 1][j + 1 + kx], o[j]);
                o[j] = fmaf((float)kv[k][2 * j + 1], rb[2 * ky][j + 2 * kx], o[j]);
            }
        }
    half4 xo;
    xo[0] = (_Float16)o[0]; xo[1] = (_Float16)o[1];
    xo[2] = (_Float16)o[2]; xo[3] = (_Float16)o[3];
    *(half4*)(x1 + (long)b * HWSZ + (long)rem * 4) = xo;
}

// ---------------------------------------------------------------------------
// Single-step prop kernel, restructured (latency-hiding version):
//  1. kv[9] global loads issued BEFORE the LDS stage loop -> their latency
//     completes under the staging loads + the compiler's vmcnt(0) drain at
//     the barrier, instead of being exposed before the FMA tail.
//  2. Row-streaming compute (r1-r5-verified D1/D2 tap structure): one 8-wide
//     row window live at a time instead of rb[5][8] -> ~35 fewer VGPRs ->
//     more waves/SIMD to overlap the remaining latency.
// ---------------------------------------------------------------------------
#define TW 64
#define TH 4
#define LW (TW + 2)
#define LROWS (TH + 4)
#define TILES_W 5
#define TILES_H (HH / TH)   // 88

#define ROWW(xs, R)                                                            \
    const float* _p = &xs[ty + (R)][4 * tx + 2];                               \
    float2 _aa = *(const float2*)(_p);                                         \
    float4 _mm = *(const float4*)(_p + 2);                                     \
    float2 _zz = *(const float2*)(_p + 6);                                     \
    float _rw[8] = {_aa.x, _aa.y, _mm.x, _mm.y, _mm.z, _mm.w, _zz.x, _zz.y};

#define D1TAP(W, KX) do {                                                      \
    oo.x = fmaf((float)W[0], _rw[0 + 1 + (KX)], oo.x);                         \
    oo.y = fmaf((float)W[2], _rw[1 + 1 + (KX)], oo.y);                         \
    oo.z = fmaf((float)W[4], _rw[2 + 1 + (KX)], oo.z);                         \
    oo.w = fmaf((float)W[6], _rw[3 + 1 + (KX)], oo.w);                         \
} while (0)

#define D2TAP(W, KX) do {                                                      \
    oo.x = fmaf((float)W[1], _rw[0 + 2 * (KX)], oo.x);                         \
    oo.y = fmaf((float)W[3], _rw[1 + 2 * (KX)], oo.y);                         \
    oo.z = fmaf((float)W[5], _rw[2 + 2 * (KX)], oo.z);                         \
    oo.w = fmaf((float)W[7], _rw[3 + 2 * (KX)], oo.w);                         \
} while (0)

template <int OUT16>
__global__ __launch_bounds__(256, 4) void prop_kernel(
    const _Float16* __restrict__ kk,
    const _Float16* __restrict__ xin, void* __restrict__ xout_) {
    __shared__ float xs[LROWS][LW * 4];

    int tid = threadIdx.x;
    int bidx = blockIdx.x;
    int tX = bidx % TILES_W;
    int r1 = bidx / TILES_W;
    int tY = r1 % TILES_H;
    int b  = r1 / TILES_H;
    int q0 = tX * TW;
    int h0 = tY * TH;

    const int tx = tid & (TW - 1);
    const int ty = tid >> 6;
    const int qa = q0 + tx;
    const bool act = (qa < WQ);
    const int h = h0 + ty;
    const long p0 = (long)h * WW + qa * 4;

    // ---- kv prefetch (issued before staging; latency hides under it) ----
    half8 kv[9];
    if (act) {
        const long kbase = ((long)b * 9 * HWSZ + p0) * 2;
#pragma unroll
        for (int k = 0; k < 9; k++)
            kv[k] = *(const half8*)(kk + kbase + (long)k * HWSZ * 2);
    }

    // ---- stage x tile + halo into LDS (fp16 -> fp32) ----
    const _Float16* xb = xin + (long)b * HWSZ;
#pragma unroll
    for (int i = tid; i < LROWS * LW; i += 256) {
        int row = i / LW;
        int qc  = i - row * LW;
        int hh  = h0 - 2 + row;
        int qg  = q0 - 1 + qc;
        float4 v = make_float4(0.f, 0.f, 0.f, 0.f);
        if (hh >= 0 && hh < HH && qg >= 0 && qg < WQ) {
            half4 hv = *(const half4*)(xb + (long)hh * WW + qg * 4);
            v = make_float4((float)hv[0], (float)hv[1], (float)hv[2], (float)hv[3]);
        }
        *(float4*)&xs[row][qc * 4] = v;
    }
    __syncthreads();

    if (!act) return;

    // ---- row-streaming 9-tap dual-dilation conv ----
    float4 oo = make_float4(0.f, 0.f, 0.f, 0.f);
    { ROWW(xs, 0); D2TAP(kv[0], 0); D2TAP(kv[1], 1); D2TAP(kv[2], 2); }
    { ROWW(xs, 1); D1TAP(kv[0], 0); D1TAP(kv[1], 1); D1TAP(kv[2], 2); }
    { ROWW(xs, 2); D1TAP(kv[3], 0); D1TAP(kv[4], 1); D1TAP(kv[5], 2);
                   D2TAP(kv[3], 0); D2TAP(kv[4], 1); D2TAP(kv[5], 2); }
    { ROWW(xs, 3); D1TAP(kv[6], 0); D1TAP(kv[7], 1); D1TAP(kv[8], 2); }
    { ROWW(xs, 4); D2TAP(kv[6], 0); D2TAP(kv[7], 1); D2TAP(kv[8], 2); }

    if (OUT16) {
        half4 xo;
        xo[0] = (_Float16)oo.x; xo[1] = (_Float16)oo.y;
        xo[2] = (_Float16)oo.z; xo[3] = (_Float16)oo.w;
        *(half4*)((_Float16*)xout_ + (long)b * HWSZ + p0) = xo;
    } else {
        *(float4*)((float*)xout_ + (long)b * HWSZ + p0) = oo;
    }
}

extern "C" void kernel_launch(void* const* d_in, const int* in_sizes, int n_in,
                              void* d_out, int out_size, void* d_ws, size_t ws_size,
                              hipStream_t stream) {
    const float* g1   = (const float*)d_in[0];
    const float* g2   = (const float*)d_in[1];
    const float* fuse = (const float*)d_in[2];
    const float* x    = (const float*)d_in[3];
    float* out = (float*)d_out;

    // ws: kk (61.6 MB) | bufA fp16 (3.4 MB) | bufB fp16 (3.4 MB)
    _Float16* kk   = (_Float16*)d_ws;
    _Float16* bufA = kk + (size_t)NB * 9 * HWSZ * 2;
    _Float16* bufB = bufA + (size_t)NB * HWSZ;

    int sm_blocks = (NQ + 255) / 256;   // 1672
    softmax_prop1_kernel<<<sm_blocks, 256, 0, stream>>>(g1, g2, fuse, x, kk, bufA);

    int pr_blocks = NB * TILES_H * TILES_W;   // 1760
    prop_kernel<1><<<pr_blocks, 256, 0, stream>>>(kk, bufA, bufB);  // step 2
    prop_kernel<1><<<pr_blocks, 256, 0, stream>>>(kk, bufB, bufA);  // step 3
    prop_kernel<1><<<pr_blocks, 256, 0, stream>>>(kk, bufA, bufB);  // step 4
    prop_kernel<1><<<pr_blocks, 256, 0, stream>>>(kk, bufB, bufA);  // step 5
    prop_kernel<1><<<pr_blocks, 256, 0, stream>>>(kk, bufA, bufB);  // step 6
    prop_kernel<1><<<pr_blocks, 256, 0, stream>>>(kk, bufB, bufA);  // step 7
    prop_kernel<0><<<pr_blocks, 256, 0, stream>>>(kk, bufA, out);   // step 8
}

// Round 8
// 246.625 us; speedup vs baseline: 3.6589x; 1.0279x over previous
//
#include <hip/hip_runtime.h>

#define HH 352
#define WW 1216
#define NB 4
#define HWSZ (HH * WW)      // 428032 pixels per plane
#define WQ 304              // quads per row
#define BHQ (HH * WQ)
#define NQ (NB * BHQ)

typedef _Float16 half4 __attribute__((ext_vector_type(4)));
typedef _Float16 half8 __attribute__((ext_vector_type(8)));

// ---------------------------------------------------------------------------
// Step 1 kernel (VERBATIM from the verified 246.5 us pipeline):
// softmax+premul for both guided tensors AND propagation step 1.
// ---------------------------------------------------------------------------
__global__ __launch_bounds__(256, 4) void softmax_prop1_kernel(
    const float* __restrict__ g1, const float* __restrict__ g2,
    const float* __restrict__ fuse, const float* __restrict__ x0,
    _Float16* __restrict__ kk, _Float16* __restrict__ x1) {
    int q = blockIdx.x * 256 + threadIdx.x;
    if (q >= NQ) return;
    int b   = q / BHQ;
    int rem = q - b * BHQ;
    int h   = rem / WQ;
    int wq  = rem - h * WQ;
    int w0  = wq * 4;
    long gbase = (long)b * 9 * HWSZ + (long)rem * 4;
    long fbase = (long)b * 2 * HWSZ + (long)rem * 4;

    float4 t[18];
#pragma unroll
    for (int k = 0; k < 9; k++) t[k]     = *(const float4*)(g1 + gbase + (long)k * HWSZ);
#pragma unroll
    for (int k = 0; k < 9; k++) t[9 + k] = *(const float4*)(g2 + gbase + (long)k * HWSZ);
    float4 f1 = *(const float4*)(fuse + fbase);
    float4 f2 = *(const float4*)(fuse + fbase + HWSZ);

    float s1[4] = {0.f, 0.f, 0.f, 0.f}, s2[4] = {0.f, 0.f, 0.f, 0.f};
#pragma unroll
    for (int k = 0; k < 9; k++) {
        t[k].x = __expf(t[k].x); s1[0] += t[k].x;
        t[k].y = __expf(t[k].y); s1[1] += t[k].y;
        t[k].z = __expf(t[k].z); s1[2] += t[k].z;
        t[k].w = __expf(t[k].w); s1[3] += t[k].w;
    }
#pragma unroll
    for (int k = 9; k < 18; k++) {
        t[k].x = __expf(t[k].x); s2[0] += t[k].x;
        t[k].y = __expf(t[k].y); s2[1] += t[k].y;
        t[k].z = __expf(t[k].z); s2[2] += t[k].z;
        t[k].w = __expf(t[k].w); s2[3] += t[k].w;
    }
    float r1[4], r2[4];
    r1[0] = f1.x / s1[0]; r1[1] = f1.y / s1[1]; r1[2] = f1.z / s1[2]; r1[3] = f1.w / s1[3];
    r2[0] = f2.x / s2[0]; r2[1] = f2.y / s2[1]; r2[2] = f2.z / s2[2]; r2[3] = f2.w / s2[3];

    long obase = gbase * 2;
    half8 kv[9];
#pragma unroll
    for (int k = 0; k < 9; k++) {
        half8 o;
        o[0] = (_Float16)(t[k].x * r1[0]); o[1] = (_Float16)(t[9 + k].x * r2[0]);
        o[2] = (_Float16)(t[k].y * r1[1]); o[3] = (_Float16)(t[9 + k].y * r2[1]);
        o[4] = (_Float16)(t[k].z * r1[2]); o[5] = (_Float16)(t[9 + k].z * r2[2]);
        o[6] = (_Float16)(t[k].w * r1[3]); o[7] = (_Float16)(t[9 + k].w * r2[3]);
        kv[k] = o;
        *(half8*)(kk + obase + (long)k * HWSZ * 2) = o;
    }

    const float* xb = x0 + (long)b * HWSZ;
    float rb[5][8];
#pragma unroll
    for (int r = 0; r < 5; r++) {
        int hh = h - 2 + r;
        bool rv = (hh >= 0) && (hh < HH);
        const float* rp = xb + (long)hh * WW;
        float4 mid = rv ? *(const float4*)(rp + w0) : make_float4(0.f, 0.f, 0.f, 0.f);
        float2 lft = (rv && w0 > 0) ? *(const float2*)(rp + w0 - 2) : make_float2(0.f, 0.f);
        float2 rgt = (rv && (w0 + 5) < WW) ? *(const float2*)(rp + w0 + 4) : make_float2(0.f, 0.f);
        rb[r][0] = lft.x; rb[r][1] = lft.y;
        rb[r][2] = mid.x; rb[r][3] = mid.y; rb[r][4] = mid.z; rb[r][5] = mid.w;
        rb[r][6] = rgt.x; rb[r][7] = rgt.y;
    }
    float o[4] = {0.f, 0.f, 0.f, 0.f};
#pragma unroll
    for (int ky = 0; ky < 3; ky++)
#pragma unroll
        for (int kx = 0; kx < 3; kx++) {
            int k = ky * 3 + kx;
#pragma unroll
            for (int j = 0; j < 4; j++) {
                o[j] = fmaf((float)kv[k][2 * j],     rb[ky + 1][j + 1 + kx], o[j]);
                o[j] = fmaf((float)kv[k][2 * j + 1], rb[2 * ky][j + 2 * kx], o[j]);
            }
        }
    half4 xo;
    xo[0] = (_Float16)o[0]; xo[1] = (_Float16)o[1];
    xo[2] = (_Float16)o[2]; xo[3] = (_Float16)o[3];
    *(half4*)(x1 + (long)b * HWSZ + (long)rem * 4) = xo;
}

// ---------------------------------------------------------------------------
// Single-step prop kernel, occupancy experiment:
//   __launch_bounds__(256, 8) -> 8 blocks/CU (32 waves), VGPR cap 64.
//   Safe because nothing big lives across the barrier: kv is loaded AFTER
//   __syncthreads (r0 ordering), compute is row-streaming (peak ~56 regs).
//   Grid (1760 blocks) now fits in one residency round (2048 slots).
// ---------------------------------------------------------------------------
#define TW 64
#define TH 4
#define LW (TW + 2)
#define LROWS (TH + 4)
#define TILES_W 5
#define TILES_H (HH / TH)   // 88

#define ROWW(xs, R)                                                            \
    const float* _p = &xs[ty + (R)][4 * tx + 2];                               \
    float2 _aa = *(const float2*)(_p);                                         \
    float4 _mm = *(const float4*)(_p + 2);                                     \
    float2 _zz = *(const float2*)(_p + 6);                                     \
    float _rw[8] = {_aa.x, _aa.y, _mm.x, _mm.y, _mm.z, _mm.w, _zz.x, _zz.y};

#define D1TAP(W, KX) do {                                                      \
    oo.x = fmaf((float)W[0], _rw[0 + 1 + (KX)], oo.x);                         \
    oo.y = fmaf((float)W[2], _rw[1 + 1 + (KX)], oo.y);                         \
    oo.z = fmaf((float)W[4], _rw[2 + 1 + (KX)], oo.z);                         \
    oo.w = fmaf((float)W[6], _rw[3 + 1 + (KX)], oo.w);                         \
} while (0)

#define D2TAP(W, KX) do {                                                      \
    oo.x = fmaf((float)W[1], _rw[0 + 2 * (KX)], oo.x);                         \
    oo.y = fmaf((float)W[3], _rw[1 + 2 * (KX)], oo.y);                         \
    oo.z = fmaf((float)W[5], _rw[2 + 2 * (KX)], oo.z);                         \
    oo.w = fmaf((float)W[7], _rw[3 + 2 * (KX)], oo.w);                         \
} while (0)

template <int OUT16>
__global__ __launch_bounds__(256, 8) void prop_kernel(
    const _Float16* __restrict__ kk,
    const _Float16* __restrict__ xin, void* __restrict__ xout_) {
    __shared__ float xs[LROWS][LW * 4];

    int tid = threadIdx.x;
    int bidx = blockIdx.x;
    int tX = bidx % TILES_W;
    int r1 = bidx / TILES_W;
    int tY = r1 % TILES_H;
    int b  = r1 / TILES_H;
    int q0 = tX * TW;
    int h0 = tY * TH;

    // ---- stage x tile + halo into LDS (fp16 -> fp32) ----
    const _Float16* xb = xin + (long)b * HWSZ;
#pragma unroll
    for (int i = tid; i < LROWS * LW; i += 256) {
        int row = i / LW;
        int qc  = i - row * LW;
        int hh  = h0 - 2 + row;
        int qg  = q0 - 1 + qc;
        float4 v = make_float4(0.f, 0.f, 0.f, 0.f);
        if (hh >= 0 && hh < HH && qg >= 0 && qg < WQ) {
            half4 hv = *(const half4*)(xb + (long)hh * WW + qg * 4);
            v = make_float4((float)hv[0], (float)hv[1], (float)hv[2], (float)hv[3]);
        }
        *(float4*)&xs[row][qc * 4] = v;
    }
    __syncthreads();

    const int tx = tid & (TW - 1);
    const int ty = tid >> 6;
    const int qa = q0 + tx;
    if (qa >= WQ) return;   // ragged last tile (after barrier)
    const int h = h0 + ty;
    const long p0 = (long)h * WW + qa * 4;

    // ---- kv loads (after barrier; live range does not cross it) ----
    half8 kv[9];
    const long kbase = ((long)b * 9 * HWSZ + p0) * 2;
#pragma unroll
    for (int k = 0; k < 9; k++)
        kv[k] = *(const half8*)(kk + kbase + (long)k * HWSZ * 2);

    // ---- row-streaming 9-tap dual-dilation conv ----
    float4 oo = make_float4(0.f, 0.f, 0.f, 0.f);
    { ROWW(xs, 0); D2TAP(kv[0], 0); D2TAP(kv[1], 1); D2TAP(kv[2], 2); }
    { ROWW(xs, 1); D1TAP(kv[0], 0); D1TAP(kv[1], 1); D1TAP(kv[2], 2); }
    { ROWW(xs, 2); D1TAP(kv[3], 0); D1TAP(kv[4], 1); D1TAP(kv[5], 2);
                   D2TAP(kv[3], 0); D2TAP(kv[4], 1); D2TAP(kv[5], 2); }
    { ROWW(xs, 3); D1TAP(kv[6], 0); D1TAP(kv[7], 1); D1TAP(kv[8], 2); }
    { ROWW(xs, 4); D2TAP(kv[6], 0); D2TAP(kv[7], 1); D2TAP(kv[8], 2); }

    if (OUT16) {
        half4 xo;
        xo[0] = (_Float16)oo.x; xo[1] = (_Float16)oo.y;
        xo[2] = (_Float16)oo.z; xo[3] = (_Float16)oo.w;
        *(half4*)((_Float16*)xout_ + (long)b * HWSZ + p0) = xo;
    } else {
        *(float4*)((float*)xout_ + (long)b * HWSZ + p0) = oo;
    }
}

extern "C" void kernel_launch(void* const* d_in, const int* in_sizes, int n_in,
                              void* d_out, int out_size, void* d_ws, size_t ws_size,
                              hipStream_t stream) {
    const float* g1   = (const float*)d_in[0];
    const float* g2   = (const float*)d_in[1];
    const float* fuse = (const float*)d_in[2];
    const float* x    = (const float*)d_in[3];
    float* out = (float*)d_out;

    // ws: kk (61.6 MB) | bufA fp16 (3.4 MB) | bufB fp16 (3.4 MB)
    _Float16* kk   = (_Float16*)d_ws;
    _Float16* bufA = kk + (size_t)NB * 9 * HWSZ * 2;
    _Float16* bufB = bufA + (size_t)NB * HWSZ;

    int sm_blocks = (NQ + 255) / 256;   // 1672
    softmax_prop1_kernel<<<sm_blocks, 256, 0, stream>>>(g1, g2, fuse, x, kk, bufA);

    int pr_blocks = NB * TILES_H * TILES_W;   // 1760
    prop_kernel<1><<<pr_blocks, 256, 0, stream>>>(kk, bufA, bufB);  // step 2
    prop_kernel<1><<<pr_blocks, 256, 0, stream>>>(kk, bufB, bufA);  // step 3
    prop_kernel<1><<<pr_blocks, 256, 0, stream>>>(kk, bufA, bufB);  // step 4
    prop_kernel<1><<<pr_blocks, 256, 0, stream>>>(kk, bufB, bufA);  // step 5
    prop_kernel<1><<<pr_blocks, 256, 0, stream>>>(kk, bufA, bufB);  // step 6
    prop_kernel<1><<<pr_blocks, 256, 0, stream>>>(kk, bufB, bufA);  // step 7
    prop_kernel<0><<<pr_blocks, 256, 0, stream>>>(kk, bufA, out);   // step 8
}